// Round 2
// baseline (171.714 us; speedup 1.0000x reference)
//
#include <hip/hip_runtime.h>

#define F_SZ 32
#define D_SZ 128
#define FD   4096                 // F_SZ * D_SZ, elements per b-row of feature
#define NPAIR 496

typedef __bf16 bf16x8 __attribute__((ext_vector_type(8)));
typedef float floatx4 __attribute__((ext_vector_type(4)));

__device__ __forceinline__ unsigned short f2bf(float f) {
  // round-to-nearest-even fp32 -> bf16
  unsigned u = __float_as_uint(f);
  u += 0x7fffu + ((u >> 16) & 1u);
  return (unsigned short)(u >> 16);
}

__device__ __forceinline__ void decode_pair(int p, int& io, int& jo) {
  int i = 0;
  while (p >= F_SZ - 1 - i) { p -= F_SZ - 1 - i; ++i; }
  io = i; jo = i + 1 + p;
}

// ---------------- Pass 1a: Zt[p][e][d] = bf16(gate(M[i][j][d][e])) ----------------
__global__ __launch_bounds__(256)
void prep_z(const float* __restrict__ mat, unsigned short* __restrict__ Zt) {
  __shared__ unsigned short tile[128 * 136];   // padded: +8 shorts/row
  int i, j; decode_pair(blockIdx.x, i, j);
  const float* zp = mat + (((size_t)i * F_SZ + j) << 14);
  const int t = threadIdx.x;
  #pragma unroll 8
  for (int it = 0; it < 64; ++it) {
    int idx = it * 256 + t;            // e fastest -> coalesced global read
    int d = idx >> 7, e = idx & 127;
    float v = zp[idx];
    float s = 1.0f / (1.0f + __expf(-v));
    float z = fminf(1.0f, fmaxf(0.0f, fmaf(s, 1.2f, -0.1f)));
    tile[e * 136 + d] = f2bf(z);       // transposed store (2-bank stride: free)
  }
  __syncthreads();
  unsigned short* op = Zt + ((size_t)blockIdx.x << 14);
  #pragma unroll 4
  for (int it = 0; it < 16; ++it) {
    int idx4 = it * 256 + t;           // 4096 ushort4 groups
    int e = idx4 >> 5, d4 = idx4 & 31;
    ushort4 v = *(const ushort4*)&tile[e * 136 + d4 * 4];
    *(ushort4*)&op[idx4 * 4] = v;      // idx4*4 == e*128 + d4*4, coalesced write
  }
}

// ---------------- Pass 1b: fb = bf16(feat), [B][F][D] ----------------
__global__ __launch_bounds__(256)
void prep_f(const float* __restrict__ feat, unsigned short* __restrict__ fb) {
  int gid = blockIdx.x * 256 + threadIdx.x;   // 262144 threads total
  #pragma unroll
  for (int k = 0; k < 4; ++k) {
    size_t idx = (size_t)k * 262144 + gid;    // float4 index, 1,048,576 total
    float4 v = *(const float4*)(feat + idx * 4);
    ushort4 h;
    h.x = f2bf(v.x); h.y = f2bf(v.y); h.z = f2bf(v.z); h.w = f2bf(v.w);
    *(ushort4*)(fb + idx * 4) = h;
  }
}

// ---------------- Pass 2: per (pair, batch-split) GEMM + fused row-dot ----------------
// 256 threads = 4 waves in 2x2 (b,e) arrangement. Wave tile 64b x 64e.
// B (Z^T) fragments live in registers for the whole block; A fragments are
// loaded directly from global bf16 feat (A-frag layout == 16 rows x 16B
// contiguous k => dwordx4 with 100% line utilization). No LDS in main loop.
__global__ __launch_bounds__(256, 2)
void pair_gemm(const unsigned short* __restrict__ Zt,
               const unsigned short* __restrict__ fb,
               const float* __restrict__ feat,
               float* __restrict__ out) {
  __shared__ float sRed[128];
  int i, j; decode_pair(blockIdx.x, i, j);
  const int t = threadIdx.x;
  const int lane = t & 63, l15 = lane & 15, quad = lane >> 4;
  const int wq = t >> 6, we = wq & 1, wb = wq >> 1;

  // B fragments: cols [we*64, we*64+64), all K. 16 x dwordx4, once per block.
  bf16x8 Bfrag[4][4];
  {
    const unsigned short* zp = Zt + ((size_t)blockIdx.x << 14);
    #pragma unroll
    for (int nf = 0; nf < 4; ++nf) {
      const int col = we * 64 + nf * 16 + l15;
      #pragma unroll
      for (int ks = 0; ks < 4; ++ks)
        Bfrag[nf][ks] = *(const bf16x8*)(zp + col * 128 + ks * 32 + quad * 8);
    }
  }

  const int bbase = blockIdx.y * 256;
  for (int it = 0; it < 2; ++it) {
    const int b0 = bbase + it * 128;
    const int rowbase = b0 + wb * 64;

    floatx4 acc[4][4];
    #pragma unroll
    for (int mf = 0; mf < 4; ++mf)
      #pragma unroll
      for (int nf = 0; nf < 4; ++nf)
        acc[mf][nf] = (floatx4){0.f, 0.f, 0.f, 0.f};

    #pragma unroll
    for (int ks = 0; ks < 4; ++ks) {
      #pragma unroll
      for (int mf = 0; mf < 4; ++mf) {
        const unsigned short* ap = fb + (size_t)(rowbase + mf * 16 + l15) * FD
                                      + i * D_SZ + ks * 32 + quad * 8;
        bf16x8 A = *(const bf16x8*)ap;
        #pragma unroll
        for (int nf = 0; nf < 4; ++nf)
          acc[mf][nf] = __builtin_amdgcn_mfma_f32_16x16x32_bf16(A, Bfrag[nf][ks], acc[mf][nf], 0, 0, 0);
      }
    }

    // Epilogue: pl[b] = sum over this wave's 64 e-cols of Y[b,e] * f_j[b,e] (fp32 f_j)
    float pl[4][4];   // [mf][reg]
    #pragma unroll
    for (int mf = 0; mf < 4; ++mf) {
      #pragma unroll
      for (int r = 0; r < 4; ++r) pl[mf][r] = 0.f;
      #pragma unroll
      for (int nf = 0; nf < 4; ++nf) {
        const int col = we * 64 + nf * 16 + l15;
        const float* fj = feat + (size_t)(rowbase + mf * 16 + quad * 4) * FD + j * D_SZ + col;
        floatx4 c = acc[mf][nf];
        pl[mf][0] += c[0] * fj[0];
        pl[mf][1] += c[1] * fj[FD];
        pl[mf][2] += c[2] * fj[2 * FD];
        pl[mf][3] += c[3] * fj[3 * FD];
      }
    }
    #pragma unroll
    for (int mf = 0; mf < 4; ++mf)
      #pragma unroll
      for (int r = 0; r < 4; ++r)
        #pragma unroll
        for (int off = 1; off < 16; off <<= 1)
          pl[mf][r] += __shfl_xor(pl[mf][r], off, 64);

    if (we == 0 && l15 == 0) {
      #pragma unroll
      for (int mf = 0; mf < 4; ++mf)
        #pragma unroll
        for (int r = 0; r < 4; ++r)
          sRed[wb * 64 + mf * 16 + quad * 4 + r] = pl[mf][r];
    }
    __syncthreads();
    if (we == 1 && l15 == 0) {
      #pragma unroll
      for (int mf = 0; mf < 4; ++mf)
        #pragma unroll
        for (int r = 0; r < 4; ++r) {
          const int lr = wb * 64 + mf * 16 + quad * 4 + r;
          out[(size_t)(b0 + lr) * (F_SZ * F_SZ) + i * F_SZ + j] = pl[mf][r] + sRed[lr];
        }
    }
    __syncthreads();   // sRed reused next iteration
  }
}

// ---------------- Fallback (round-1 kernel) if ws is too small ----------------
#define LDA  136
#define LDB  136
__device__ __forceinline__ float bf2f(unsigned short h) {
  return __uint_as_float(((unsigned)h) << 16);
}

__global__ __launch_bounds__(256, 2)
void interaction_pair_kernel(const float* __restrict__ feat,
                             const float* __restrict__ mat,
                             float* __restrict__ out) {
  __shared__ unsigned short sA[128 * LDA];
  __shared__ unsigned short sBT[128 * LDB];
  const int t = threadIdx.x;
  const int w = t >> 6, lane = t & 63, l15 = lane & 15, quad = lane >> 4;
  int i, j; decode_pair(blockIdx.x, i, j);
  {
    const float* zp = mat + (((size_t)i * F_SZ + j) << 14);
    #pragma unroll 8
    for (int it = 0; it < 64; ++it) {
      int idx = it * 256 + t;
      int d = idx >> 7, e = idx & 127;
      float v = zp[idx];
      float s = 1.0f / (1.0f + __expf(-v));
      float z = fminf(1.0f, fmaxf(0.0f, fmaf(s, 1.2f, -0.1f)));
      sBT[e * LDB + d] = f2bf(z);
    }
  }
  for (int bt = 0; bt < 8; ++bt) {
    const int b0 = bt * 128;
    #pragma unroll 4
    for (int it = 0; it < 16; ++it) {
      int idx4 = it * 256 + t;
      int r = idx4 >> 5, c4 = idx4 & 31;
      const float4 v = *(const float4*)(feat + (size_t)(b0 + r) * FD + i * D_SZ + c4 * 4);
      ushort4 h;
      h.x = f2bf(v.x); h.y = f2bf(v.y); h.z = f2bf(v.z); h.w = f2bf(v.w);
      *(ushort4*)(&sA[r * LDA + c4 * 4]) = h;
    }
    __syncthreads();
    floatx4 acc[2][8];
    #pragma unroll
    for (int mf = 0; mf < 2; ++mf)
      #pragma unroll
      for (int nf = 0; nf < 8; ++nf)
        acc[mf][nf] = (floatx4){0.f, 0.f, 0.f, 0.f};
    #pragma unroll
    for (int k0 = 0; k0 < 128; k0 += 32) {
      const int kc = k0 + quad * 8;
      bf16x8 a0 = *(const bf16x8*)&sA[(w * 32 +      l15) * LDA + kc];
      bf16x8 a1 = *(const bf16x8*)&sA[(w * 32 + 16 + l15) * LDA + kc];
      #pragma unroll
      for (int nf = 0; nf < 8; ++nf) {
        bf16x8 bfr = *(const bf16x8*)&sBT[(nf * 16 + l15) * LDB + kc];
        acc[0][nf] = __builtin_amdgcn_mfma_f32_16x16x32_bf16(a0, bfr, acc[0][nf], 0, 0, 0);
        acc[1][nf] = __builtin_amdgcn_mfma_f32_16x16x32_bf16(a1, bfr, acc[1][nf], 0, 0, 0);
      }
    }
    #pragma unroll
    for (int mf = 0; mf < 2; ++mf) {
      float pl[4] = {0.f, 0.f, 0.f, 0.f};
      const int rb = w * 32 + mf * 16 + quad * 4;
      #pragma unroll
      for (int nf = 0; nf < 8; ++nf) {
        const int col = nf * 16 + l15;
        const float* fj = feat + (size_t)(b0 + rb) * FD + j * D_SZ + col;
        floatx4 c = acc[mf][nf];
        pl[0] += c[0] * fj[0];
        pl[1] += c[1] * fj[FD];
        pl[2] += c[2] * fj[2 * FD];
        pl[3] += c[3] * fj[3 * FD];
      }
      #pragma unroll
      for (int off = 1; off < 16; off <<= 1) {
        pl[0] += __shfl_xor(pl[0], off, 64);
        pl[1] += __shfl_xor(pl[1], off, 64);
        pl[2] += __shfl_xor(pl[2], off, 64);
        pl[3] += __shfl_xor(pl[3], off, 64);
      }
      if (l15 == 0) {
        size_t ob = (size_t)(b0 + rb) * (F_SZ * F_SZ) + (size_t)i * F_SZ + j;
        out[ob]                   = pl[0];
        out[ob + 1 * F_SZ * F_SZ] = pl[1];
        out[ob + 2 * F_SZ * F_SZ] = pl[2];
        out[ob + 3 * F_SZ * F_SZ] = pl[3];
      }
    }
    __syncthreads();
  }
}

extern "C" void kernel_launch(void* const* d_in, const int* in_sizes, int n_in,
                              void* d_out, int out_size, void* d_ws, size_t ws_size,
                              hipStream_t stream) {
  const float* feat = (const float*)d_in[0];   // [B, F, D] fp32
  const float* mat  = (const float*)d_in[1];   // [F, F, D, D] fp32
  float* out = (float*)d_out;                  // [B, F, F] fp32

  hipMemsetAsync(out, 0, (size_t)out_size * sizeof(float), stream);

  const size_t zt_bytes = (size_t)NPAIR * D_SZ * D_SZ * sizeof(unsigned short); // 16,252,928
  const size_t fb_bytes = (size_t)1024 * FD * sizeof(unsigned short);           //  8,388,608

  if (ws_size >= zt_bytes + fb_bytes) {
    unsigned short* Zt = (unsigned short*)d_ws;
    unsigned short* fbuf = Zt + (size_t)NPAIR * D_SZ * D_SZ;
    prep_z<<<dim3(NPAIR), dim3(256), 0, stream>>>(mat, Zt);
    prep_f<<<dim3(1024), dim3(256), 0, stream>>>(feat, fbuf);
    pair_gemm<<<dim3(NPAIR, 4), dim3(256), 0, stream>>>(Zt, fbuf, feat, out);
  } else {
    interaction_pair_kernel<<<dim3(NPAIR), dim3(256), 0, stream>>>(feat, mat, out);
  }
}